// Round 2
// baseline (456.533 us; speedup 1.0000x reference)
//
#include <hip/hip_runtime.h>
#include <hip/hip_bf16.h>
#include <type_traits>

// ---------------------------------------------------------------------------
// CausalSelfAttention: x[4,2048,1024] f32, w_qkv[3072,1024], w_out[1024,1024]
// Pipeline: cvt(bf16) -> GEMM qkv -> causal flash attn -> GEMM out (f32)
// ---------------------------------------------------------------------------

typedef __attribute__((ext_vector_type(8))) short bf16x8;
typedef __attribute__((ext_vector_type(4))) float f32x4;

#define LDS_AS(p) ((__attribute__((address_space(3))) void*)(p))
#define GLB_AS(p) ((const __attribute__((address_space(1))) void*)(p))

// ----------------------------- fp32 -> bf16 --------------------------------
__global__ __launch_bounds__(256) void cvt_f32_bf16(const float* __restrict__ in,
                                                    __hip_bfloat16* __restrict__ out,
                                                    int n4) {
  int i = blockIdx.x * 256 + threadIdx.x;
  if (i >= n4) return;
  float4 v = reinterpret_cast<const float4*>(in)[i];
  __hip_bfloat16 b0 = __float2bfloat16(v.x);
  __hip_bfloat16 b1 = __float2bfloat16(v.y);
  __hip_bfloat16 b2 = __float2bfloat16(v.z);
  __hip_bfloat16 b3 = __float2bfloat16(v.w);
  ushort4 u;
  u.x = *reinterpret_cast<unsigned short*>(&b0);
  u.y = *reinterpret_cast<unsigned short*>(&b1);
  u.z = *reinterpret_cast<unsigned short*>(&b2);
  u.w = *reinterpret_cast<unsigned short*>(&b3);
  reinterpret_cast<ushort4*>(out)[i] = u;
}

// --------------------- GEMM: C[M,N] = A[M,K] * B[N,K]^T --------------------
template <typename TOUT>
__global__ __launch_bounds__(256) void gemm_bt(const __hip_bfloat16* __restrict__ A,
                                               const __hip_bfloat16* __restrict__ B,
                                               TOUT* __restrict__ C,
                                               int M, int N, int K) {
  __shared__ __hip_bfloat16 As[128 * 64];
  __shared__ __hip_bfloat16 Bs[128 * 64];
  const int tid = threadIdx.x;
  const int lane = tid & 63;
  const int wid = tid >> 6;
  const int l15 = lane & 15, l4 = lane >> 4;
  const int m0 = blockIdx.x * 128, n0 = blockIdx.y * 128;
  const int wr = (wid >> 1) * 64;
  const int wc = (wid & 1) * 64;
  f32x4 acc[4][4] = {};

  for (int kt = 0; kt < K; kt += 64) {
#pragma unroll
    for (int i = 0; i < 4; ++i) {
      const int slot = i * 256 + tid;
      const int row = slot >> 3, c8 = slot & 7;
      __builtin_amdgcn_global_load_lds(GLB_AS(A + (size_t)(m0 + row) * K + kt + c8 * 8),
                                       LDS_AS((char*)As + slot * 16), 16, 0, 0);
      __builtin_amdgcn_global_load_lds(GLB_AS(B + (size_t)(n0 + row) * K + kt + c8 * 8),
                                       LDS_AS((char*)Bs + slot * 16), 16, 0, 0);
    }
    __syncthreads();
#pragma unroll
    for (int kk = 0; kk < 2; ++kk) {
      bf16x8 af[4], bfr[4];
#pragma unroll
      for (int mi = 0; mi < 4; ++mi)
        af[mi] = *reinterpret_cast<const bf16x8*>(As + (wr + mi * 16 + l15) * 64 + kk * 32 + l4 * 8);
#pragma unroll
      for (int ni = 0; ni < 4; ++ni)
        bfr[ni] = *reinterpret_cast<const bf16x8*>(Bs + (wc + ni * 16 + l15) * 64 + kk * 32 + l4 * 8);
#pragma unroll
      for (int mi = 0; mi < 4; ++mi)
#pragma unroll
        for (int ni = 0; ni < 4; ++ni)
          acc[mi][ni] = __builtin_amdgcn_mfma_f32_16x16x32_bf16(af[mi], bfr[ni], acc[mi][ni], 0, 0, 0);
    }
    __syncthreads();
  }
#pragma unroll
  for (int mi = 0; mi < 4; ++mi)
#pragma unroll
    for (int ni = 0; ni < 4; ++ni)
#pragma unroll
      for (int j = 0; j < 4; ++j) {
        const int m = m0 + wr + mi * 16 + l4 * 4 + j;
        const int n = n0 + wc + ni * 16 + l15;
        if constexpr (std::is_same<TOUT, float>::value)
          C[(size_t)m * N + n] = acc[mi][ni][j];
        else
          C[(size_t)m * N + n] = __float2bfloat16(acc[mi][ni][j]);
      }
}

// --------------------------- causal flash attn -----------------------------
// Swapped-QK design: S^T = mfma(A=K, B=Q) puts q = lane&15 (lane-local),
// kv in regs -> in-lane softmax with only 2 shfl_xor reductions.
// V^T staged via kv-pair packed b32 writes with (jj+c8) rotation (no 16-way
// conflicts). Next tile's K/V global loads issued before compute (T14).
__global__ __launch_bounds__(256) void attn_causal(const __hip_bfloat16* __restrict__ qkv,
                                                   __hip_bfloat16* __restrict__ o) {
  constexpr int T = 2048, F = 3072, C = 1024;
  __shared__ __hip_bfloat16 Ks[64 * 72];        // K tile  [kv][d], pad 72
  __shared__ __hip_bfloat16 Vts[64 * 72];       // V tile transposed [d][kv], pad 72
  __shared__ __hip_bfloat16 Ps[4][16 * 72];     // per-wave P [q][kv], pad 72
  const int tid = threadIdx.x;
  const int wid = tid >> 6, lane = tid & 63;
  const int l15 = lane & 15, l4 = lane >> 4;
  const int qb = blockIdx.x, h = blockIdx.y, b = blockIdx.z;
  const __hip_bfloat16* base = qkv + (size_t)b * T * F;
  const int q0 = qb * 64;
  const int qw = q0 + wid * 16;
  const int hoff = h * 64;

  // Q fragment (B operand): lane holds Q[qw+l15][kk*32 + l4*8 .. +7]
  bf16x8 aq[2];
#pragma unroll
  for (int kk = 0; kk < 2; ++kk)
    aq[kk] = *reinterpret_cast<const bf16x8*>(base + (size_t)(qw + l15) * F + hoff + kk * 32 + l4 * 8);

  // staging thread mapping: V: kv-pair r2, d-octet c8; K: 2 slots of 8 rows
  const int r2 = tid >> 3, c8 = tid & 7;

  f32x4 acc[4] = {};
  float mrun = -1e30f, lrun = 0.f;              // per-lane state for q = qw+l15
  constexpr float SC = 0.125f * 1.44269504088896f;  // 1/sqrt(64) * log2(e)

  bf16x8 kreg0, kreg1, vreg0, vreg1;
  {
    const int s0 = tid, s1 = 256 + tid;
    kreg0 = *reinterpret_cast<const bf16x8*>(base + (size_t)(s0 >> 3) * F + hoff + C + (s0 & 7) * 8);
    kreg1 = *reinterpret_cast<const bf16x8*>(base + (size_t)(s1 >> 3) * F + hoff + C + (s1 & 7) * 8);
    const size_t vr = (size_t)(2 * r2) * F + hoff + 2 * C + c8 * 8;
    vreg0 = *reinterpret_cast<const bf16x8*>(base + vr);
    vreg1 = *reinterpret_cast<const bf16x8*>(base + vr + F);
  }

  for (int kv = 0; kv <= qb; ++kv) {
    const int k0 = kv * 64;
    // ---- pack V pair-dwords and rotate left by c8 (all static indices) ----
    unsigned int pkr[8];
    {
      const unsigned short* a0 = reinterpret_cast<const unsigned short*>(&vreg0);
      const unsigned short* a1 = reinterpret_cast<const unsigned short*>(&vreg1);
      unsigned int pk[8], t[8];
#pragma unroll
      for (int j = 0; j < 8; ++j) pk[j] = (unsigned int)a0[j] | ((unsigned int)a1[j] << 16);
#pragma unroll
      for (int j = 0; j < 8; ++j) t[j] = (c8 & 4) ? pk[(j + 4) & 7] : pk[j];
#pragma unroll
      for (int j = 0; j < 8; ++j) pkr[j] = (c8 & 2) ? t[(j + 2) & 7] : t[j];
#pragma unroll
      for (int j = 0; j < 8; ++j) t[j] = (c8 & 1) ? pkr[(j + 1) & 7] : pkr[j];
#pragma unroll
      for (int j = 0; j < 8; ++j) pkr[j] = t[j];
    }
    __syncthreads();  // previous tile fully consumed
    {
      const int s0 = tid, s1 = 256 + tid;
      *reinterpret_cast<bf16x8*>(&Ks[(s0 >> 3) * 72 + (s0 & 7) * 8]) = kreg0;
      *reinterpret_cast<bf16x8*>(&Ks[(s1 >> 3) * 72 + (s1 & 7) * 8]) = kreg1;
#pragma unroll
      for (int jj = 0; jj < 8; ++jj) {
        const int cj = (jj + c8) & 7;
        const int d = c8 * 8 + cj;
        *reinterpret_cast<unsigned int*>(&Vts[d * 72 + 2 * r2]) = pkr[jj];
      }
    }
    __syncthreads();  // staged tile visible
    if (kv < qb) {    // T14: issue next tile's loads; latency hides under compute
      const int kn = k0 + 64;
      const int s0 = tid, s1 = 256 + tid;
      kreg0 = *reinterpret_cast<const bf16x8*>(base + (size_t)(kn + (s0 >> 3)) * F + hoff + C + (s0 & 7) * 8);
      kreg1 = *reinterpret_cast<const bf16x8*>(base + (size_t)(kn + (s1 >> 3)) * F + hoff + C + (s1 & 7) * 8);
      const size_t vr = (size_t)(kn + 2 * r2) * F + hoff + 2 * C + c8 * 8;
      vreg0 = *reinterpret_cast<const bf16x8*>(base + vr);
      vreg1 = *reinterpret_cast<const bf16x8*>(base + vr + F);
    }

    // ---- S^T = K Q^T : lane holds S[q=qw+l15][kv = k0+16kt+4*l4+j] ----
    f32x4 s[4];
#pragma unroll
    for (int kt = 0; kt < 4; ++kt) {
      f32x4 z = {};
#pragma unroll
      for (int kk = 0; kk < 2; ++kk) {
        bf16x8 kf = *reinterpret_cast<const bf16x8*>(Ks + (kt * 16 + l15) * 72 + kk * 32 + l4 * 8);
        z = __builtin_amdgcn_mfma_f32_16x16x32_bf16(kf, aq[kk], z, 0, 0, 0);
      }
      s[kt] = z;
    }

    // ---- mask (diagonal tile only) + scale into log2 domain ----
    const int qg = qw + l15;
    if (kv == qb) {
#pragma unroll
      for (int kt = 0; kt < 4; ++kt)
#pragma unroll
        for (int j = 0; j < 4; ++j) {
          const int kg = k0 + kt * 16 + l4 * 4 + j;
          s[kt][j] = (kg <= qg) ? s[kt][j] * SC : -1e30f;
        }
    } else {
#pragma unroll
      for (int kt = 0; kt < 4; ++kt)
#pragma unroll
        for (int j = 0; j < 4; ++j) s[kt][j] *= SC;
    }

    // ---- online softmax: in-lane tree + 2 cross-group shuffles ----
    float m0 = fmaxf(fmaxf(s[0][0], s[0][1]), fmaxf(s[0][2], s[0][3]));
    float m1 = fmaxf(fmaxf(s[1][0], s[1][1]), fmaxf(s[1][2], s[1][3]));
    float m2 = fmaxf(fmaxf(s[2][0], s[2][1]), fmaxf(s[2][2], s[2][3]));
    float m3 = fmaxf(fmaxf(s[3][0], s[3][1]), fmaxf(s[3][2], s[3][3]));
    float mt = fmaxf(fmaxf(m0, m1), fmaxf(m2, m3));
    mt = fmaxf(mt, __shfl_xor(mt, 16, 64));
    mt = fmaxf(mt, __shfl_xor(mt, 32, 64));
    const float mnew = fmaxf(mrun, mt);
    const float sco = exp2f(mrun - mnew);
    float rs = 0.f;
#pragma unroll
    for (int kt = 0; kt < 4; ++kt) {
      float p0 = exp2f(s[kt][0] - mnew), p1 = exp2f(s[kt][1] - mnew);
      float p2 = exp2f(s[kt][2] - mnew), p3 = exp2f(s[kt][3] - mnew);
      s[kt][0] = p0; s[kt][1] = p1; s[kt][2] = p2; s[kt][3] = p3;
      rs += (p0 + p1) + (p2 + p3);
    }
    rs += __shfl_xor(rs, 16, 64);
    rs += __shfl_xor(rs, 32, 64);
    lrun = lrun * sco + rs;
    mrun = mnew;

    // ---- rescale acc (rows q = qw + l4*4 + j need factor from lane l4*4+j) --
#pragma unroll
    for (int j = 0; j < 4; ++j) {
      const float fj = __shfl(sco, l4 * 4 + j, 64);
#pragma unroll
      for (int di = 0; di < 4; ++di) acc[di][j] *= fj;
    }

    // ---- P -> per-wave LDS (4x ds_write_b64, uniform banks) -> A-frags ----
    __hip_bfloat16* pw = Ps[wid];
#pragma unroll
    for (int kt = 0; kt < 4; ++kt) {
      __hip_bfloat16 e0 = __float2bfloat16(s[kt][0]);
      __hip_bfloat16 e1 = __float2bfloat16(s[kt][1]);
      __hip_bfloat16 e2 = __float2bfloat16(s[kt][2]);
      __hip_bfloat16 e3 = __float2bfloat16(s[kt][3]);
      unsigned int w0 = (unsigned int)*reinterpret_cast<unsigned short*>(&e0) |
                        ((unsigned int)*reinterpret_cast<unsigned short*>(&e1) << 16);
      unsigned int w1 = (unsigned int)*reinterpret_cast<unsigned short*>(&e2) |
                        ((unsigned int)*reinterpret_cast<unsigned short*>(&e3) << 16);
      unsigned long long dw = (unsigned long long)w0 | ((unsigned long long)w1 << 32);
      *reinterpret_cast<unsigned long long*>(&pw[l15 * 72 + kt * 16 + l4 * 4]) = dw;
    }
    bf16x8 pa0 = *reinterpret_cast<const bf16x8*>(pw + l15 * 72 + l4 * 8);
    bf16x8 pa1 = *reinterpret_cast<const bf16x8*>(pw + l15 * 72 + 32 + l4 * 8);

    // ---- O += P V ----
#pragma unroll
    for (int di = 0; di < 4; ++di) {
      bf16x8 v0 = *reinterpret_cast<const bf16x8*>(Vts + (di * 16 + l15) * 72 + l4 * 8);
      bf16x8 v1 = *reinterpret_cast<const bf16x8*>(Vts + (di * 16 + l15) * 72 + 32 + l4 * 8);
      acc[di] = __builtin_amdgcn_mfma_f32_16x16x32_bf16(pa0, v0, acc[di], 0, 0, 0);
      acc[di] = __builtin_amdgcn_mfma_f32_16x16x32_bf16(pa1, v1, acc[di], 0, 0, 0);
    }
  }

  // ---- normalize + write (acc rows q = qw + l4*4 + j, cols d = di*16+l15) --
  const float inv = 1.0f / lrun;
#pragma unroll
  for (int j = 0; j < 4; ++j) {
    const float invj = __shfl(inv, l4 * 4 + j, 64);
    const int qg = qw + l4 * 4 + j;
    __hip_bfloat16* op = o + (size_t)(b * T + qg) * C + hoff + l15;
#pragma unroll
    for (int di = 0; di < 4; ++di)
      op[di * 16] = __float2bfloat16(acc[di][j] * invj);
  }
}

// ------------------------------- launcher ----------------------------------
extern "C" void kernel_launch(void* const* d_in, const int* in_sizes, int n_in,
                              void* d_out, int out_size, void* d_ws, size_t ws_size,
                              hipStream_t stream) {
  const float* x = (const float*)d_in[0];
  const float* w_qkv = (const float*)d_in[1];
  const float* w_out = (const float*)d_in[2];
  float* out = (float*)d_out;

  constexpr int B = 4, T = 2048, C = 1024, F = 3 * C;
  constexpr int M = B * T;

  __hip_bfloat16* xb = (__hip_bfloat16*)d_ws;            // M*C
  __hip_bfloat16* wqkvb = xb + (size_t)M * C;            // F*C
  __hip_bfloat16* woutb = wqkvb + (size_t)F * C;         // C*C
  __hip_bfloat16* qkvb = woutb + (size_t)C * C;          // M*F
  __hip_bfloat16* attnb = qkvb + (size_t)M * F;          // M*C

  cvt_f32_bf16<<<(M * C / 4 + 255) / 256, 256, 0, stream>>>(x, xb, M * C / 4);
  cvt_f32_bf16<<<(F * C / 4 + 255) / 256, 256, 0, stream>>>(w_qkv, wqkvb, F * C / 4);
  cvt_f32_bf16<<<(C * C / 4 + 255) / 256, 256, 0, stream>>>(w_out, woutb, C * C / 4);

  gemm_bt<__hip_bfloat16><<<dim3(M / 128, F / 128), 256, 0, stream>>>(xb, wqkvb, qkvb, M, F, C);

  attn_causal<<<dim3(T / 64, 16, B), 256, 0, stream>>>(qkvb, attnb);

  gemm_bt<float><<<dim3(M / 128, C / 128), 256, 0, stream>>>(attnb, woutb, out, M, C, C);
}

// Round 5
// 244.796 us; speedup vs baseline: 1.8650x; 1.8650x over previous
//
#include <hip/hip_runtime.h>
#include <hip/hip_bf16.h>
#include <type_traits>

// ---------------------------------------------------------------------------
// CausalSelfAttention: x[4,2048,1024] f32, w_qkv[3072,1024], w_out[1024,1024]
// Pipeline: cvt(bf16) -> GEMM qkv -> causal flash attn -> GEMM out (f32)
// ---------------------------------------------------------------------------

typedef __attribute__((ext_vector_type(8))) short bf16x8;
typedef __attribute__((ext_vector_type(4))) float f32x4;

#define LDS_AS(p) ((__attribute__((address_space(3))) void*)(p))
#define GLB_AS(p) ((const __attribute__((address_space(1))) void*)(p))

// ----------------------------- fp32 -> bf16 --------------------------------
__global__ __launch_bounds__(256) void cvt_f32_bf16(const float* __restrict__ in,
                                                    __hip_bfloat16* __restrict__ out,
                                                    int n4) {
  int i = blockIdx.x * 256 + threadIdx.x;
  if (i >= n4) return;
  float4 v = reinterpret_cast<const float4*>(in)[i];
  __hip_bfloat16 b0 = __float2bfloat16(v.x);
  __hip_bfloat16 b1 = __float2bfloat16(v.y);
  __hip_bfloat16 b2 = __float2bfloat16(v.z);
  __hip_bfloat16 b3 = __float2bfloat16(v.w);
  ushort4 u;
  u.x = *reinterpret_cast<unsigned short*>(&b0);
  u.y = *reinterpret_cast<unsigned short*>(&b1);
  u.z = *reinterpret_cast<unsigned short*>(&b2);
  u.w = *reinterpret_cast<unsigned short*>(&b3);
  reinterpret_cast<ushort4*>(out)[i] = u;
}

// --------------------- GEMM: C[M,N] = A[M,K] * B[N,K]^T --------------------
template <typename TOUT>
__global__ __launch_bounds__(256) void gemm_bt(const __hip_bfloat16* __restrict__ A,
                                               const __hip_bfloat16* __restrict__ B,
                                               TOUT* __restrict__ C,
                                               int M, int N, int K) {
  __shared__ __hip_bfloat16 As[128 * 64];
  __shared__ __hip_bfloat16 Bs[128 * 64];
  const int tid = threadIdx.x;
  const int lane = tid & 63;
  const int wid = tid >> 6;
  const int l15 = lane & 15, l4 = lane >> 4;
  const int m0 = blockIdx.x * 128, n0 = blockIdx.y * 128;
  const int wr = (wid >> 1) * 64;
  const int wc = (wid & 1) * 64;
  f32x4 acc[4][4] = {};

  for (int kt = 0; kt < K; kt += 64) {
#pragma unroll
    for (int i = 0; i < 4; ++i) {
      const int slot = i * 256 + tid;
      const int row = slot >> 3, c8 = slot & 7;
      __builtin_amdgcn_global_load_lds(GLB_AS(A + (size_t)(m0 + row) * K + kt + c8 * 8),
                                       LDS_AS((char*)As + slot * 16), 16, 0, 0);
      __builtin_amdgcn_global_load_lds(GLB_AS(B + (size_t)(n0 + row) * K + kt + c8 * 8),
                                       LDS_AS((char*)Bs + slot * 16), 16, 0, 0);
    }
    __syncthreads();
#pragma unroll
    for (int kk = 0; kk < 2; ++kk) {
      bf16x8 af[4], bfr[4];
#pragma unroll
      for (int mi = 0; mi < 4; ++mi)
        af[mi] = *reinterpret_cast<const bf16x8*>(As + (wr + mi * 16 + l15) * 64 + kk * 32 + l4 * 8);
#pragma unroll
      for (int ni = 0; ni < 4; ++ni)
        bfr[ni] = *reinterpret_cast<const bf16x8*>(Bs + (wc + ni * 16 + l15) * 64 + kk * 32 + l4 * 8);
#pragma unroll
      for (int mi = 0; mi < 4; ++mi)
#pragma unroll
        for (int ni = 0; ni < 4; ++ni)
          acc[mi][ni] = __builtin_amdgcn_mfma_f32_16x16x32_bf16(af[mi], bfr[ni], acc[mi][ni], 0, 0, 0);
    }
    __syncthreads();
  }
#pragma unroll
  for (int mi = 0; mi < 4; ++mi)
#pragma unroll
    for (int ni = 0; ni < 4; ++ni)
#pragma unroll
      for (int j = 0; j < 4; ++j) {
        const int m = m0 + wr + mi * 16 + l4 * 4 + j;
        const int n = n0 + wc + ni * 16 + l15;
        if constexpr (std::is_same<TOUT, float>::value)
          C[(size_t)m * N + n] = acc[mi][ni][j];
        else
          C[(size_t)m * N + n] = __float2bfloat16(acc[mi][ni][j]);
      }
}

// --------------------------- causal flash attn -----------------------------
// 512 threads = 8 waves. Waves 0-3 own q-tile x (256 rows), waves 4-7 own
// q-tile 7-x -> per-SIMD work uniform, one shared KV staging stream.
// Each wave: 4 Q-frags x 16 rows. Both matmuls swapped (A=K / A=V^T) so q =
// lane&15 everywhere: softmax + rescale + epilogue are broadcast-free.
__global__ __launch_bounds__(512, 2) void attn_causal(const __hip_bfloat16* __restrict__ qkv,
                                                      __hip_bfloat16* __restrict__ o) {
  constexpr int T = 2048, F = 3072, C = 1024;
  __shared__ __hip_bfloat16 Ks[64 * 72];        // K tile  [kv][d], pad 72
  __shared__ __hip_bfloat16 Vts[64 * 72];       // V^T tile [d][kv], pad 72
  __shared__ __hip_bfloat16 Ps[8][16 * 72];     // per-wave P [q][kv], pad 72
  const int tid = threadIdx.x;
  const int wid = tid >> 6, lane = tid & 63;
  const int l15 = lane & 15, l4 = lane >> 4;
  const int x = blockIdx.x, h = blockIdx.y, b = blockIdx.z;
  const int qt = (wid < 4) ? x : (7 - x);       // this wave's 256-row q-tile
  const int nt = 4 * (7 - x) + 4;               // tiles staged by the block
  const int tmax = 4 * qt + (wid & 3);          // this wave's diagonal tile
  const int hoff = h * 64;
  const __hip_bfloat16* base = qkv + (size_t)b * T * F;
  const int Q0 = qt * 256 + (wid & 3) * 64;     // wave's first q row

  constexpr float SC = 0.125f * 1.44269504088896f;  // 1/sqrt(64) * log2(e)

  // Q frags (B operand)
  bf16x8 aq[4][2];
#pragma unroll
  for (int f = 0; f < 4; ++f)
#pragma unroll
    for (int kk = 0; kk < 2; ++kk)
      aq[f][kk] = *reinterpret_cast<const bf16x8*>(base + (size_t)(Q0 + f * 16 + l15) * F + hoff + kk * 32 + l4 * 8);

  f32x4 acc[4][4] = {};   // [frag][di]: O[q=Q0+f*16+l15][d=di*16+l4*4+j]
  float mrun[4], lrun[4];
#pragma unroll
  for (int f = 0; f < 4; ++f) { mrun[f] = -1e30f; lrun[f] = 0.f; }

  // staging roles: waves 0-3 stage V (2 rows/thread), waves 4-7 stage K
  const int sV = tid;        // valid when wid<4: r2=sV>>3, c8=sV&7
  const int sK = tid - 256;  // valid when wid>=4
  bf16x8 sreg0, sreg1;
  if (wid < 4) {
    const size_t vr = (size_t)(2 * (sV >> 3)) * F + hoff + 2 * C + (sV & 7) * 8;
    sreg0 = *reinterpret_cast<const bf16x8*>(base + vr);
    sreg1 = *reinterpret_cast<const bf16x8*>(base + vr + F);
  } else {
    sreg0 = *reinterpret_cast<const bf16x8*>(base + (size_t)(sK >> 3) * F + hoff + C + (sK & 7) * 8);
    sreg1 = *reinterpret_cast<const bf16x8*>(base + (size_t)(32 + (sK >> 3)) * F + hoff + C + (sK & 7) * 8);
  }

  for (int t = 0; t < nt; ++t) {
    // ---- pack V pair-dwords, rotate by c8 (bank-spread; static idx only) ---
    unsigned pkr[8];
    if (wid < 4) {
      const unsigned short* a0 = reinterpret_cast<const unsigned short*>(&sreg0);
      const unsigned short* a1 = reinterpret_cast<const unsigned short*>(&sreg1);
      const int c8 = sV & 7;
      unsigned pk[8], tw[8];
#pragma unroll
      for (int j = 0; j < 8; ++j) pk[j] = (unsigned)a0[j] | ((unsigned)a1[j] << 16);
#pragma unroll
      for (int j = 0; j < 8; ++j) tw[j] = (c8 & 4) ? pk[(j + 4) & 7] : pk[j];
#pragma unroll
      for (int j = 0; j < 8; ++j) pkr[j] = (c8 & 2) ? tw[(j + 2) & 7] : tw[j];
#pragma unroll
      for (int j = 0; j < 8; ++j) tw[j] = (c8 & 1) ? pkr[(j + 1) & 7] : pkr[j];
#pragma unroll
      for (int j = 0; j < 8; ++j) pkr[j] = tw[j];
    }
    __syncthreads();  // previous tile fully consumed
    if (wid < 4) {
      const int r2 = sV >> 3, c8 = sV & 7;
#pragma unroll
      for (int jj = 0; jj < 8; ++jj) {
        const int d = c8 * 8 + ((jj + c8) & 7);
        *reinterpret_cast<unsigned*>(&Vts[d * 72 + 2 * r2]) = pkr[jj];
      }
    } else {
      *reinterpret_cast<bf16x8*>(&Ks[(sK >> 3) * 72 + (sK & 7) * 8]) = sreg0;
      *reinterpret_cast<bf16x8*>(&Ks[(32 + (sK >> 3)) * 72 + (sK & 7) * 8]) = sreg1;
    }
    __syncthreads();  // staged tile visible
    if (t + 1 < nt) {  // T14: next tile's loads hide under compute
      const int kn = (t + 1) * 64;
      if (wid < 4) {
        const size_t vr = (size_t)(kn + 2 * (sV >> 3)) * F + hoff + 2 * C + (sV & 7) * 8;
        sreg0 = *reinterpret_cast<const bf16x8*>(base + vr);
        sreg1 = *reinterpret_cast<const bf16x8*>(base + vr + F);
      } else {
        sreg0 = *reinterpret_cast<const bf16x8*>(base + (size_t)(kn + (sK >> 3)) * F + hoff + C + (sK & 7) * 8);
        sreg1 = *reinterpret_cast<const bf16x8*>(base + (size_t)(kn + 32 + (sK >> 3)) * F + hoff + C + (sK & 7) * 8);
      }
    }
    if (t > tmax) continue;  // wave-uniform skip; barriers are at loop top
    const bool diag = (t == tmax);

    // ---- hoist K / V^T fragments (shared by all 4 q-frags) ----
    bf16x8 kf[4][2], vf[4][2];
#pragma unroll
    for (int kt = 0; kt < 4; ++kt)
#pragma unroll
      for (int kk = 0; kk < 2; ++kk)
        kf[kt][kk] = *reinterpret_cast<const bf16x8*>(Ks + (kt * 16 + l15) * 72 + kk * 32 + l4 * 8);
#pragma unroll
    for (int di = 0; di < 4; ++di)
#pragma unroll
      for (int kk = 0; kk < 2; ++kk)
        vf[di][kk] = *reinterpret_cast<const bf16x8*>(Vts + (di * 16 + l15) * 72 + kk * 32 + l4 * 8);

    __hip_bfloat16* pw = Ps[wid];
#pragma unroll
    for (int f = 0; f < 4; ++f) {
      // ---- S^T = K Q^T : lane holds S[q=Q0+f*16+l15][kv=kt*16+l4*4+j] ----
      f32x4 s[4];
#pragma unroll
      for (int kt = 0; kt < 4; ++kt) {
        f32x4 z = {};
        z = __builtin_amdgcn_mfma_f32_16x16x32_bf16(kf[kt][0], aq[f][0], z, 0, 0, 0);
        z = __builtin_amdgcn_mfma_f32_16x16x32_bf16(kf[kt][1], aq[f][1], z, 0, 0, 0);
        s[kt] = z;
      }

      // ---- mask (diag tile: tile-local kv <= tile-local q) + scale ----
      if (diag) {
        const int ql = f * 16 + l15;
#pragma unroll
        for (int kt = 0; kt < 4; ++kt)
#pragma unroll
          for (int j = 0; j < 4; ++j) {
            const int kvl = kt * 16 + l4 * 4 + j;
            s[kt][j] = (kvl <= ql) ? s[kt][j] * SC : -1e30f;
          }
      } else {
#pragma unroll
        for (int kt = 0; kt < 4; ++kt)
#pragma unroll
          for (int j = 0; j < 4; ++j) s[kt][j] *= SC;
      }

      // ---- online softmax: in-lane tree + 2 cross-group shuffles ----
      float mt = -1e30f;
#pragma unroll
      for (int kt = 0; kt < 4; ++kt)
        mt = fmaxf(mt, fmaxf(fmaxf(s[kt][0], s[kt][1]), fmaxf(s[kt][2], s[kt][3])));
      mt = fmaxf(mt, __shfl_xor(mt, 16, 64));
      mt = fmaxf(mt, __shfl_xor(mt, 32, 64));
      const float mnew = fmaxf(mrun[f], mt);
      const float sco = exp2f(mrun[f] - mnew);
      float rs = 0.f;
#pragma unroll
      for (int kt = 0; kt < 4; ++kt) {
        float p0 = exp2f(s[kt][0] - mnew), p1 = exp2f(s[kt][1] - mnew);
        float p2 = exp2f(s[kt][2] - mnew), p3 = exp2f(s[kt][3] - mnew);
        s[kt][0] = p0; s[kt][1] = p1; s[kt][2] = p2; s[kt][3] = p3;
        rs += (p0 + p1) + (p2 + p3);
      }
      rs += __shfl_xor(rs, 16, 64);
      rs += __shfl_xor(rs, 32, 64);
      lrun[f] = lrun[f] * sco + rs;
      mrun[f] = mnew;
#pragma unroll
      for (int di = 0; di < 4; ++di) acc[f][di] *= sco;

      // ---- P -> per-wave LDS (4x ds_write_b64) -> B-operand frags ----
#pragma unroll
      for (int kt = 0; kt < 4; ++kt) {
        __hip_bfloat16 e0 = __float2bfloat16(s[kt][0]);
        __hip_bfloat16 e1 = __float2bfloat16(s[kt][1]);
        __hip_bfloat16 e2 = __float2bfloat16(s[kt][2]);
        __hip_bfloat16 e3 = __float2bfloat16(s[kt][3]);
        unsigned w0 = (unsigned)*reinterpret_cast<unsigned short*>(&e0) |
                      ((unsigned)*reinterpret_cast<unsigned short*>(&e1) << 16);
        unsigned w1 = (unsigned)*reinterpret_cast<unsigned short*>(&e2) |
                      ((unsigned)*reinterpret_cast<unsigned short*>(&e3) << 16);
        unsigned long long dw = (unsigned long long)w0 | ((unsigned long long)w1 << 32);
        *reinterpret_cast<unsigned long long*>(&pw[l15 * 72 + kt * 16 + l4 * 4]) = dw;
      }
      // Ordering fence: the writes above and reads below alias through
      // different TBAA types; force program order + drain DS queue.
      asm volatile("s_waitcnt lgkmcnt(0)" ::: "memory");
      bf16x8 pa0 = *reinterpret_cast<const bf16x8*>(pw + l15 * 72 + l4 * 8);
      bf16x8 pa1 = *reinterpret_cast<const bf16x8*>(pw + l15 * 72 + 32 + l4 * 8);

      // ---- O^T += V^T P^T : A=V^T rows d, B=P rows q -> acc q=l15 ----
#pragma unroll
      for (int di = 0; di < 4; ++di) {
        acc[f][di] = __builtin_amdgcn_mfma_f32_16x16x32_bf16(vf[di][0], pa0, acc[f][di], 0, 0, 0);
        acc[f][di] = __builtin_amdgcn_mfma_f32_16x16x32_bf16(vf[di][1], pa1, acc[f][di], 0, 0, 0);
      }
    }
  }

  // ---- normalize + write: lane has O[q=Q0+f*16+l15][d=di*16+l4*4+(0..3)] ---
#pragma unroll
  for (int f = 0; f < 4; ++f) {
    const float inv = 1.0f / lrun[f];
    __hip_bfloat16* op = o + (size_t)((size_t)b * T + Q0 + f * 16 + l15) * C + hoff;
#pragma unroll
    for (int di = 0; di < 4; ++di) {
      ushort4 u;
      __hip_bfloat16 e0 = __float2bfloat16(acc[f][di][0] * inv);
      __hip_bfloat16 e1 = __float2bfloat16(acc[f][di][1] * inv);
      __hip_bfloat16 e2 = __float2bfloat16(acc[f][di][2] * inv);
      __hip_bfloat16 e3 = __float2bfloat16(acc[f][di][3] * inv);
      u.x = *reinterpret_cast<unsigned short*>(&e0);
      u.y = *reinterpret_cast<unsigned short*>(&e1);
      u.z = *reinterpret_cast<unsigned short*>(&e2);
      u.w = *reinterpret_cast<unsigned short*>(&e3);
      *reinterpret_cast<ushort4*>(op + di * 16 + l4 * 4) = u;
    }
  }
}

// ------------------------------- launcher ----------------------------------
extern "C" void kernel_launch(void* const* d_in, const int* in_sizes, int n_in,
                              void* d_out, int out_size, void* d_ws, size_t ws_size,
                              hipStream_t stream) {
  const float* x = (const float*)d_in[0];
  const float* w_qkv = (const float*)d_in[1];
  const float* w_out = (const float*)d_in[2];
  float* out = (float*)d_out;

  constexpr int B = 4, T = 2048, C = 1024, F = 3 * C;
  constexpr int M = B * T;

  __hip_bfloat16* xb = (__hip_bfloat16*)d_ws;            // M*C
  __hip_bfloat16* wqkvb = xb + (size_t)M * C;            // F*C
  __hip_bfloat16* woutb = wqkvb + (size_t)F * C;         // C*C
  __hip_bfloat16* qkvb = woutb + (size_t)C * C;          // M*F
  __hip_bfloat16* attnb = qkvb + (size_t)M * F;          // M*C

  cvt_f32_bf16<<<(M * C / 4 + 255) / 256, 256, 0, stream>>>(x, xb, M * C / 4);
  cvt_f32_bf16<<<(F * C / 4 + 255) / 256, 256, 0, stream>>>(w_qkv, wqkvb, F * C / 4);
  cvt_f32_bf16<<<(C * C / 4 + 255) / 256, 256, 0, stream>>>(w_out, woutb, C * C / 4);

  gemm_bt<__hip_bfloat16><<<dim3(M / 128, F / 128), 256, 0, stream>>>(xb, wqkvb, qkvb, M, F, C);

  attn_causal<<<dim3(4, 16, B), 512, 0, stream>>>(qkvb, attnb);

  gemm_bt<float><<<dim3(M / 128, C / 128), 256, 0, stream>>>(attnb, woutb, out, M, C, C);
}

// Round 6
// 231.135 us; speedup vs baseline: 1.9752x; 1.0591x over previous
//
#include <hip/hip_runtime.h>
#include <hip/hip_bf16.h>
#include <type_traits>

// ---------------------------------------------------------------------------
// CausalSelfAttention: x[4,2048,1024] f32, w_qkv[3072,1024], w_out[1024,1024]
// Pipeline: cvt(bf16) -> GEMM qkv -> causal flash attn -> GEMM out (f32)
// ---------------------------------------------------------------------------

typedef __attribute__((ext_vector_type(8))) short bf16x8;
typedef __attribute__((ext_vector_type(4))) float f32x4;

#define LDS_AS(p) ((__attribute__((address_space(3))) void*)(p))
#define GLB_AS(p) ((const __attribute__((address_space(1))) void*)(p))

// ----------------------------- fp32 -> bf16 --------------------------------
__global__ __launch_bounds__(256) void cvt_f32_bf16(const float* __restrict__ in,
                                                    __hip_bfloat16* __restrict__ out,
                                                    int n4) {
  int i = blockIdx.x * 256 + threadIdx.x;
  if (i >= n4) return;
  float4 v = reinterpret_cast<const float4*>(in)[i];
  __hip_bfloat16 b0 = __float2bfloat16(v.x);
  __hip_bfloat16 b1 = __float2bfloat16(v.y);
  __hip_bfloat16 b2 = __float2bfloat16(v.z);
  __hip_bfloat16 b3 = __float2bfloat16(v.w);
  ushort4 u;
  u.x = *reinterpret_cast<unsigned short*>(&b0);
  u.y = *reinterpret_cast<unsigned short*>(&b1);
  u.z = *reinterpret_cast<unsigned short*>(&b2);
  u.w = *reinterpret_cast<unsigned short*>(&b3);
  reinterpret_cast<ushort4*>(out)[i] = u;
}

// --------------------- GEMM: C[M,N] = A[M,K] * B[N,K]^T --------------------
template <typename TOUT>
__global__ __launch_bounds__(256) void gemm_bt(const __hip_bfloat16* __restrict__ A,
                                               const __hip_bfloat16* __restrict__ B,
                                               TOUT* __restrict__ C,
                                               int M, int N, int K) {
  __shared__ __hip_bfloat16 As[128 * 64];
  __shared__ __hip_bfloat16 Bs[128 * 64];
  const int tid = threadIdx.x;
  const int lane = tid & 63;
  const int wid = tid >> 6;
  const int l15 = lane & 15, l4 = lane >> 4;
  const int m0 = blockIdx.x * 128, n0 = blockIdx.y * 128;
  const int wr = (wid >> 1) * 64;
  const int wc = (wid & 1) * 64;
  f32x4 acc[4][4] = {};

  for (int kt = 0; kt < K; kt += 64) {
#pragma unroll
    for (int i = 0; i < 4; ++i) {
      const int slot = i * 256 + tid;
      const int row = slot >> 3, c8 = slot & 7;
      __builtin_amdgcn_global_load_lds(GLB_AS(A + (size_t)(m0 + row) * K + kt + c8 * 8),
                                       LDS_AS((char*)As + slot * 16), 16, 0, 0);
      __builtin_amdgcn_global_load_lds(GLB_AS(B + (size_t)(n0 + row) * K + kt + c8 * 8),
                                       LDS_AS((char*)Bs + slot * 16), 16, 0, 0);
    }
    __syncthreads();
#pragma unroll
    for (int kk = 0; kk < 2; ++kk) {
      bf16x8 af[4], bfr[4];
#pragma unroll
      for (int mi = 0; mi < 4; ++mi)
        af[mi] = *reinterpret_cast<const bf16x8*>(As + (wr + mi * 16 + l15) * 64 + kk * 32 + l4 * 8);
#pragma unroll
      for (int ni = 0; ni < 4; ++ni)
        bfr[ni] = *reinterpret_cast<const bf16x8*>(Bs + (wc + ni * 16 + l15) * 64 + kk * 32 + l4 * 8);
#pragma unroll
      for (int mi = 0; mi < 4; ++mi)
#pragma unroll
        for (int ni = 0; ni < 4; ++ni)
          acc[mi][ni] = __builtin_amdgcn_mfma_f32_16x16x32_bf16(af[mi], bfr[ni], acc[mi][ni], 0, 0, 0);
    }
    __syncthreads();
  }
#pragma unroll
  for (int mi = 0; mi < 4; ++mi)
#pragma unroll
    for (int ni = 0; ni < 4; ++ni)
#pragma unroll
      for (int j = 0; j < 4; ++j) {
        const int m = m0 + wr + mi * 16 + l4 * 4 + j;
        const int n = n0 + wc + ni * 16 + l15;
        if constexpr (std::is_same<TOUT, float>::value)
          C[(size_t)m * N + n] = acc[mi][ni][j];
        else
          C[(size_t)m * N + n] = __float2bfloat16(acc[mi][ni][j]);
      }
}

// --------------------------- causal flash attn -----------------------------
// 512 threads = 8 waves; waves 0-3 own q-tile x, waves 4-7 own 7-x (uniform
// per-SIMD work). 4 Q-frags/wave; both matmuls swapped so q=lane&15 is local.
// LDS K/V double-buffered: ONE barrier per tile; staging overlaps compute.
// Q prescaled by 1/sqrt(64)*log2e; defer-max (THR=8) skips acc rescale.
__global__ __launch_bounds__(512, 2) void attn_causal(const __hip_bfloat16* __restrict__ qkv,
                                                      __hip_bfloat16* __restrict__ o) {
  constexpr int T = 2048, F = 3072, C = 1024;
  __shared__ __hip_bfloat16 Ks[2][64 * 72];     // K tile  [kv][d], pad 72
  __shared__ __hip_bfloat16 Vts[2][64 * 72];    // V^T tile [d][kv], pad 72
  __shared__ __hip_bfloat16 Ps[8][16 * 72];     // per-wave P [q][kv], pad 72
  const int tid = threadIdx.x;
  const int wid = tid >> 6, lane = tid & 63;
  const int l15 = lane & 15, l4 = lane >> 4;
  const int x = blockIdx.x, h = blockIdx.y, b = blockIdx.z;
  const int qt = (wid < 4) ? x : (7 - x);       // this wave's 256-row q-tile
  const int nt = 4 * (7 - x) + 4;               // tiles staged by the block
  const int tmax = 4 * qt + (wid & 3);          // this wave's diagonal tile
  const int hoff = h * 64;
  const __hip_bfloat16* base = qkv + (size_t)b * T * F;
  const int Q0 = qt * 256 + (wid & 3) * 64;     // wave's first q row

  constexpr float SC = 0.125f * 1.44269504088896f;  // 1/sqrt(64) * log2(e)

  // Q frags (B operand), prescaled by SC -> S comes out in log2 domain
  bf16x8 aq[4][2];
#pragma unroll
  for (int f = 0; f < 4; ++f)
#pragma unroll
    for (int kk = 0; kk < 2; ++kk) {
      bf16x8 q = *reinterpret_cast<const bf16x8*>(base + (size_t)(Q0 + f * 16 + l15) * F + hoff + kk * 32 + l4 * 8);
#pragma unroll
      for (int e = 0; e < 8; ++e) {
        const unsigned short raw = (unsigned short)q[e];
        const float fv = __uint_as_float((unsigned)raw << 16) * SC;
        __hip_bfloat16 qs = __float2bfloat16(fv);
        q[e] = *reinterpret_cast<short*>(&qs);
      }
      aq[f][kk] = q;
    }

  f32x4 acc[4][4] = {};   // [frag][di]: O[q=Q0+f*16+l15][d=di*16+l4*4+j]
  float mrun[4], lrun[4];
#pragma unroll
  for (int f = 0; f < 4; ++f) { mrun[f] = -1e30f; lrun[f] = 0.f; }

  // staging roles: waves 0-3 stage V (2 rows/thread), waves 4-7 stage K
  const int sV = tid;        // valid when wid<4: r2=sV>>3, c8=sV&7
  const int sK = tid - 256;  // valid when wid>=4
  bf16x8 sreg0, sreg1;
  if (wid < 4) {
    const size_t vr = (size_t)(2 * (sV >> 3)) * F + hoff + 2 * C + (sV & 7) * 8;
    sreg0 = *reinterpret_cast<const bf16x8*>(base + vr);
    sreg1 = *reinterpret_cast<const bf16x8*>(base + vr + F);
  } else {
    sreg0 = *reinterpret_cast<const bf16x8*>(base + (size_t)(sK >> 3) * F + hoff + C + (sK & 7) * 8);
    sreg1 = *reinterpret_cast<const bf16x8*>(base + (size_t)(32 + (sK >> 3)) * F + hoff + C + (sK & 7) * 8);
  }

  for (int t = 0; t < nt; ++t) {
    const int cur = t & 1;
    // ---- write staged tile t (in sregs) into buf[cur] ----
    if (wid < 4) {
      // pack V pair-dwords, rotate by c8 (bank-spread; static idx only)
      const unsigned short* a0 = reinterpret_cast<const unsigned short*>(&sreg0);
      const unsigned short* a1 = reinterpret_cast<const unsigned short*>(&sreg1);
      const int c8 = sV & 7, r2 = sV >> 3;
      unsigned pk[8], tw[8], pkr[8];
#pragma unroll
      for (int j = 0; j < 8; ++j) pk[j] = (unsigned)a0[j] | ((unsigned)a1[j] << 16);
#pragma unroll
      for (int j = 0; j < 8; ++j) tw[j] = (c8 & 4) ? pk[(j + 4) & 7] : pk[j];
#pragma unroll
      for (int j = 0; j < 8; ++j) pkr[j] = (c8 & 2) ? tw[(j + 2) & 7] : tw[j];
#pragma unroll
      for (int j = 0; j < 8; ++j) tw[j] = (c8 & 1) ? pkr[(j + 1) & 7] : pkr[j];
#pragma unroll
      for (int jj = 0; jj < 8; ++jj) {
        const int d = c8 * 8 + ((jj + c8) & 7);
        *reinterpret_cast<unsigned*>(&Vts[cur][d * 72 + 2 * r2]) = tw[jj];
      }
    } else {
      *reinterpret_cast<bf16x8*>(&Ks[cur][(sK >> 3) * 72 + (sK & 7) * 8]) = sreg0;
      *reinterpret_cast<bf16x8*>(&Ks[cur][(32 + (sK >> 3)) * 72 + (sK & 7) * 8]) = sreg1;
    }
    __syncthreads();   // buf[cur] visible; buf[cur^1] free for next iter
    // ---- issue loads for tile t+1 (land during compute below) ----
    if (t + 1 < nt) {
      const int kn = (t + 1) * 64;
      if (wid < 4) {
        const size_t vr = (size_t)(kn + 2 * (sV >> 3)) * F + hoff + 2 * C + (sV & 7) * 8;
        sreg0 = *reinterpret_cast<const bf16x8*>(base + vr);
        sreg1 = *reinterpret_cast<const bf16x8*>(base + vr + F);
      } else {
        sreg0 = *reinterpret_cast<const bf16x8*>(base + (size_t)(kn + (sK >> 3)) * F + hoff + C + (sK & 7) * 8);
        sreg1 = *reinterpret_cast<const bf16x8*>(base + (size_t)(kn + 32 + (sK >> 3)) * F + hoff + C + (sK & 7) * 8);
      }
    }
    if (t > tmax) continue;  // wave-uniform skip; barrier is at loop top
    const bool diag = (t == tmax);

    // ---- hoist K / V^T fragments (shared by all 4 q-frags) ----
    bf16x8 kf[4][2], vf[4][2];
#pragma unroll
    for (int kt = 0; kt < 4; ++kt)
#pragma unroll
      for (int kk = 0; kk < 2; ++kk)
        kf[kt][kk] = *reinterpret_cast<const bf16x8*>(&Ks[cur][(kt * 16 + l15) * 72 + kk * 32 + l4 * 8]);
#pragma unroll
    for (int di = 0; di < 4; ++di)
#pragma unroll
      for (int kk = 0; kk < 2; ++kk)
        vf[di][kk] = *reinterpret_cast<const bf16x8*>(&Vts[cur][(di * 16 + l15) * 72 + kk * 32 + l4 * 8]);

    __hip_bfloat16* pw = Ps[wid];
#pragma unroll
    for (int f = 0; f < 4; ++f) {
      // ---- S^T = K Q^T (log2 domain; Q prescaled) ----
      f32x4 s[4];
#pragma unroll
      for (int kt = 0; kt < 4; ++kt) {
        f32x4 z = {};
        z = __builtin_amdgcn_mfma_f32_16x16x32_bf16(kf[kt][0], aq[f][0], z, 0, 0, 0);
        z = __builtin_amdgcn_mfma_f32_16x16x32_bf16(kf[kt][1], aq[f][1], z, 0, 0, 0);
        s[kt] = z;
      }
      // ---- causal mask (diag tile only; pure select) ----
      if (diag) {
        const int ql = f * 16 + l15;
#pragma unroll
        for (int kt = 0; kt < 4; ++kt)
#pragma unroll
          for (int j = 0; j < 4; ++j) {
            const int kvl = kt * 16 + l4 * 4 + j;
            s[kt][j] = (kvl <= ql) ? s[kt][j] : -1e30f;
          }
      }

      // ---- online softmax (max3-friendly tree + 2 shuffles) ----
      float t0 = fmaxf(fmaxf(s[0][0], s[0][1]), s[0][2]);
      float t1 = fmaxf(fmaxf(s[0][3], s[1][0]), s[1][1]);
      float t2 = fmaxf(fmaxf(s[1][2], s[1][3]), s[2][0]);
      float t3 = fmaxf(fmaxf(s[2][1], s[2][2]), s[2][3]);
      float t4 = fmaxf(fmaxf(s[3][0], s[3][1]), s[3][2]);
      float mt = fmaxf(fmaxf(fmaxf(t0, t1), fmaxf(t2, t3)), fmaxf(t4, s[3][3]));
      mt = fmaxf(mt, __shfl_xor(mt, 16, 64));
      mt = fmaxf(mt, __shfl_xor(mt, 32, 64));
      // defer-max: if max grew by <= 8 (log2), keep old max, skip rescale
      const bool defer = __all(mt <= mrun[f] + 8.f);
      const float mnew = defer ? mrun[f] : fmaxf(mrun[f], mt);
      float rs = 0.f;
#pragma unroll
      for (int kt = 0; kt < 4; ++kt) {
        float p0 = exp2f(s[kt][0] - mnew), p1 = exp2f(s[kt][1] - mnew);
        float p2 = exp2f(s[kt][2] - mnew), p3 = exp2f(s[kt][3] - mnew);
        s[kt][0] = p0; s[kt][1] = p1; s[kt][2] = p2; s[kt][3] = p3;
        rs += (p0 + p1) + (p2 + p3);
      }
      rs += __shfl_xor(rs, 16, 64);
      rs += __shfl_xor(rs, 32, 64);
      if (defer) {
        lrun[f] += rs;
      } else {
        const float sco = exp2f(mrun[f] - mnew);
        lrun[f] = lrun[f] * sco + rs;
        mrun[f] = mnew;
#pragma unroll
        for (int di = 0; di < 4; ++di) acc[f][di] *= sco;
      }

      // ---- P -> per-wave LDS (cvt_pk + 4x ds_write_b64) -> B-frags ----
#pragma unroll
      for (int kt = 0; kt < 4; ++kt) {
        unsigned w0, w1;
        asm("v_cvt_pk_bf16_f32 %0, %1, %2" : "=v"(w0) : "v"(s[kt][0]), "v"(s[kt][1]));
        asm("v_cvt_pk_bf16_f32 %0, %1, %2" : "=v"(w1) : "v"(s[kt][2]), "v"(s[kt][3]));
        unsigned long long dw = (unsigned long long)w0 | ((unsigned long long)w1 << 32);
        *reinterpret_cast<unsigned long long*>(&pw[l15 * 72 + kt * 16 + l4 * 4]) = dw;
      }
      // Ordering fence: writes above / reads below alias via different TBAA
      // types; force program order + drain DS queue (rule-18 family).
      asm volatile("s_waitcnt lgkmcnt(0)" ::: "memory");
      bf16x8 pa0 = *reinterpret_cast<const bf16x8*>(pw + l15 * 72 + l4 * 8);
      bf16x8 pa1 = *reinterpret_cast<const bf16x8*>(pw + l15 * 72 + 32 + l4 * 8);

      // ---- O^T += V^T P^T ----
#pragma unroll
      for (int di = 0; di < 4; ++di) {
        acc[f][di] = __builtin_amdgcn_mfma_f32_16x16x32_bf16(vf[di][0], pa0, acc[f][di], 0, 0, 0);
        acc[f][di] = __builtin_amdgcn_mfma_f32_16x16x32_bf16(vf[di][1], pa1, acc[f][di], 0, 0, 0);
      }
    }
  }

  // ---- normalize + write: lane has O[q=Q0+f*16+l15][d=di*16+l4*4+(0..3)] ---
#pragma unroll
  for (int f = 0; f < 4; ++f) {
    const float inv = 1.0f / lrun[f];
    __hip_bfloat16* op = o + (size_t)((size_t)b * T + Q0 + f * 16 + l15) * C + hoff;
#pragma unroll
    for (int di = 0; di < 4; ++di) {
      ushort4 u;
      __hip_bfloat16 e0 = __float2bfloat16(acc[f][di][0] * inv);
      __hip_bfloat16 e1 = __float2bfloat16(acc[f][di][1] * inv);
      __hip_bfloat16 e2 = __float2bfloat16(acc[f][di][2] * inv);
      __hip_bfloat16 e3 = __float2bfloat16(acc[f][di][3] * inv);
      u.x = *reinterpret_cast<unsigned short*>(&e0);
      u.y = *reinterpret_cast<unsigned short*>(&e1);
      u.z = *reinterpret_cast<unsigned short*>(&e2);
      u.w = *reinterpret_cast<unsigned short*>(&e3);
      *reinterpret_cast<ushort4*>(op + di * 16 + l4 * 4) = u;
    }
  }
}

// ------------------------------- launcher ----------------------------------
extern "C" void kernel_launch(void* const* d_in, const int* in_sizes, int n_in,
                              void* d_out, int out_size, void* d_ws, size_t ws_size,
                              hipStream_t stream) {
  const float* x = (const float*)d_in[0];
  const float* w_qkv = (const float*)d_in[1];
  const float* w_out = (const float*)d_in[2];
  float* out = (float*)d_out;

  constexpr int B = 4, T = 2048, C = 1024, F = 3 * C;
  constexpr int M = B * T;

  __hip_bfloat16* xb = (__hip_bfloat16*)d_ws;            // M*C
  __hip_bfloat16* wqkvb = xb + (size_t)M * C;            // F*C
  __hip_bfloat16* woutb = wqkvb + (size_t)F * C;         // C*C
  __hip_bfloat16* qkvb = woutb + (size_t)C * C;          // M*F
  __hip_bfloat16* attnb = qkvb + (size_t)M * F;          // M*C

  cvt_f32_bf16<<<(M * C / 4 + 255) / 256, 256, 0, stream>>>(x, xb, M * C / 4);
  cvt_f32_bf16<<<(F * C / 4 + 255) / 256, 256, 0, stream>>>(w_qkv, wqkvb, F * C / 4);
  cvt_f32_bf16<<<(C * C / 4 + 255) / 256, 256, 0, stream>>>(w_out, woutb, C * C / 4);

  gemm_bt<__hip_bfloat16><<<dim3(M / 128, F / 128), 256, 0, stream>>>(xb, wqkvb, qkvb, M, F, C);

  attn_causal<<<dim3(4, 16, B), 512, 0, stream>>>(qkvb, attnb);

  gemm_bt<float><<<dim3(M / 128, C / 128), 256, 0, stream>>>(attnb, woutb, out, M, C, C);
}